// Round 1
// baseline (3309.691 us; speedup 1.0000x reference)
//
#include <hip/hip_runtime.h>
#include <hip/hip_fp16.h>

#define TSEQ   2048
#define NB     64
#define NE     256
#define NH     256
#define NG     768
#define TCH    128
#define NCHUNK (TSEQ / TCH)

using half2_t = __attribute__((ext_vector_type(2))) _Float16;

union U4 {
  uint4 q;
  half2_t h[4];
};

__device__ __forceinline__ float dot2f(half2_t a, half2_t b, float c) {
#if __has_builtin(__builtin_amdgcn_fdot2)
  return __builtin_amdgcn_fdot2(a, b, c, false);
#else
  return c + (float)a[0] * (float)b[0] + (float)a[1] * (float)b[1];
#endif
}

// ---------------------------------------------------------------------------
// Pack w_hh (fp32 [768][256]) into fp16 pairs, layout: w16[(k2b*768 + row)*4 + q]
// where k2 = k2b*4 + q covers elements (2*k2, 2*k2+1). Gives coalesced,
// 16B-aligned uint4 per (row, k2b).
// ---------------------------------------------------------------------------
__global__ void prep_whh(const float* __restrict__ whh, unsigned int* __restrict__ w16) {
  int idx = blockIdx.x * 256 + threadIdx.x;
  if (idx >= 128 * NG) return;
  int row = idx % NG;
  int k2  = idx / NG;
  half2_t p;
  p[0] = (_Float16)whh[row * NH + 2 * k2];
  p[1] = (_Float16)whh[row * NH + 2 * k2 + 1];
  union { half2_t h; unsigned int u; } cvt;
  cvt.h = p;
  w16[(((k2 >> 2) * NG + row) << 2) | (k2 & 3)] = cvt.u;
}

// ---------------------------------------------------------------------------
// gi[t_local][b][g] = emb[seq[b][t]] . w_ih[g] + b_ih[g]   (fp32)
// grid = (TCH, 4), block = 256. Tile: 64 batch rows x 192 gates, K blocked by 64.
// ---------------------------------------------------------------------------
__global__ __launch_bounds__(256) void gi_kernel(
    const int* __restrict__ seq, const float* __restrict__ emb,
    const float* __restrict__ wih, const float* __restrict__ bih,
    float* __restrict__ gi, int t0)
{
  __shared__ __align__(16) float xs[64][68];
  __shared__ __align__(16) float ws[192][68];
  __shared__ int tok[64];
  const int tid = threadIdx.x;
  const int t   = t0 + blockIdx.x;
  const int g0  = blockIdx.y * 192;
  if (tid < 64) tok[tid] = seq[tid * TSEQ + t];   // seq[b][t], b = tid
  const int ty = tid >> 4, tx = tid & 15;
  float acc[4][12];
  #pragma unroll
  for (int i = 0; i < 4; ++i)
    #pragma unroll
    for (int jj = 0; jj < 12; ++jj) acc[i][jj] = 0.f;

  for (int kb = 0; kb < 4; ++kb) {
    __syncthreads();   // also covers tok visibility on first iteration
    // stage x tile: 64 rows x 64 floats (16 float4 per row)
    #pragma unroll
    for (int it = 0; it < 4; ++it) {
      int i = it * 256 + tid;
      int r = i >> 4, c = i & 15;
      float4 v = *(const float4*)(emb + (size_t)tok[r] * NE + kb * 64 + c * 4);
      *(float4*)(&xs[r][c * 4]) = v;
    }
    // stage w tile: 192 rows x 64 floats
    #pragma unroll
    for (int it = 0; it < 12; ++it) {
      int i = it * 256 + tid;
      int r = i >> 4, c = i & 15;
      float4 v = *(const float4*)(wih + (size_t)(g0 + r) * NE + kb * 64 + c * 4);
      *(float4*)(&ws[r][c * 4]) = v;
    }
    __syncthreads();
    for (int k4 = 0; k4 < 16; ++k4) {
      float xf[4][4], wf[12][4];
      #pragma unroll
      for (int i = 0; i < 4; ++i)
        *(float4*)xf[i] = *(const float4*)(&xs[ty * 4 + i][k4 * 4]);
      #pragma unroll
      for (int jj = 0; jj < 12; ++jj)
        *(float4*)wf[jj] = *(const float4*)(&ws[tx + 16 * jj][k4 * 4]);
      #pragma unroll
      for (int i = 0; i < 4; ++i)
        #pragma unroll
        for (int jj = 0; jj < 12; ++jj)
          #pragma unroll
          for (int c = 0; c < 4; ++c)
            acc[i][jj] += xf[i][c] * wf[jj][c];
    }
  }
  // epilogue: g mapping is g = g0 + tx + 16*jj -> fully coalesced stores
  #pragma unroll
  for (int i = 0; i < 4; ++i) {
    int b = ty * 4 + i;
    float* dst = gi + ((size_t)(blockIdx.x * 64 + b)) * NG + g0;
    #pragma unroll
    for (int jj = 0; jj < 12; ++jj) {
      int g = tx + 16 * jj;
      dst[g] = acc[i][jj] + bih[g0 + g];
    }
  }
}

// ---------------------------------------------------------------------------
// Recurrence: one workgroup per batch element. 512 threads = 8 waves.
// thread (j = tid&255, s = tid>>8) owns k-half s of gate rows {j, 256+j, 512+j},
// weights held ENTIRELY in registers as fp16 pairs (3 x 16 uint4 = 192 VGPRs).
// h kept fp32 in registers of s==0 threads; fp16 copy in LDS for the dots.
// ---------------------------------------------------------------------------
__global__ __launch_bounds__(512, 2) void rec_kernel(
    const unsigned int* __restrict__ w16,
    const float* __restrict__ gi,
    const float* __restrict__ bhh,
    float* __restrict__ h_state,
    float* __restrict__ out,     // d_out on last chunk, else nullptr
    int chunk)
{
  __shared__ __align__(16) _Float16 h16[NH];
  __shared__ float red[NH][3];
  const int b    = blockIdx.x;
  const int tid  = threadIdx.x;
  const int j    = tid & 255;
  const int s    = tid >> 8;
  const int k2b0 = s << 4;

  // preload this thread's weight fragments into registers
  uint4 wrv[16], wzv[16], wnv[16];
  #pragma unroll
  for (int i = 0; i < 16; ++i) {
    const int kk = k2b0 + i;
    const unsigned int* base = w16 + (((size_t)kk * NG) << 2);
    wrv[i] = *(const uint4*)(base + ((size_t)j << 2));
    wzv[i] = *(const uint4*)(base + ((size_t)(NH + j) << 2));
    wnv[i] = *(const uint4*)(base + ((size_t)(2 * NH + j) << 2));
  }

  float hreg = 0.f, bhr = 0.f, bhz = 0.f, bhn = 0.f;
  if (s == 0) {
    if (chunk != 0) hreg = h_state[b * NH + j];
    h16[j] = (_Float16)hreg;
    bhr = bhh[j]; bhz = bhh[NH + j]; bhn = bhh[2 * NH + j];
  }
  __syncthreads();

  for (int t = 0; t < TCH; ++t) {
    float gr = 0.f, gz = 0.f, gn = 0.f;
    if (s == 0) {  // prefetch input-side gates (independent of h -> hides under dots)
      const float* g = gi + ((size_t)(t * NB + b)) * NG;
      gr = g[j]; gz = g[NH + j]; gn = g[2 * NH + j];
    }
    float ar = 0.f, az = 0.f, an = 0.f;
    #pragma unroll
    for (int i = 0; i < 16; ++i) {
      const int kk = k2b0 + i;
      U4 hu; hu.q = *(const uint4*)((const char*)h16 + (kk << 4));  // wave-uniform -> broadcast
      U4 ru; ru.q = wrv[i];
      U4 zu; zu.q = wzv[i];
      U4 nu; nu.q = wnv[i];
      #pragma unroll
      for (int q = 0; q < 4; ++q) {
        ar = dot2f(hu.h[q], ru.h[q], ar);
        az = dot2f(hu.h[q], zu.h[q], az);
        an = dot2f(hu.h[q], nu.h[q], an);
      }
    }
    if (s == 1) { red[j][0] = ar; red[j][1] = az; red[j][2] = an; }
    __syncthreads();
    if (s == 0) {
      ar += red[j][0]; az += red[j][1]; an += red[j][2];
      float r = 1.f / (1.f + expf(-(gr + ar + bhr)));
      float z = 1.f / (1.f + expf(-(gz + az + bhz)));
      float n = tanhf(gn + r * (an + bhn));
      hreg = (1.f - z) * n + z * hreg;
      h16[j] = (_Float16)hreg;
    }
    __syncthreads();
  }

  if (s == 0) {
    h_state[b * NH + j] = hreg;
    if (out) out[b * NH + j] = hreg;
  }
}

extern "C" void kernel_launch(void* const* d_in, const int* in_sizes, int n_in,
                              void* d_out, int out_size, void* d_ws, size_t ws_size,
                              hipStream_t stream) {
  (void)in_sizes; (void)n_in; (void)out_size; (void)ws_size;
  const int*   seq  = (const int*)d_in[0];
  const float* emb  = (const float*)d_in[1];
  const float* wih  = (const float*)d_in[2];
  const float* whh  = (const float*)d_in[3];
  const float* bih  = (const float*)d_in[4];
  const float* bhh  = (const float*)d_in[5];
  float* out = (float*)d_out;
  char*  ws  = (char*)d_ws;

  unsigned int* w16     = (unsigned int*)(ws);              // 393,216 B
  float*        h_state = (float*)(ws + 393216);            //  65,536 B
  float*        gi      = (float*)(ws + 393216 + 65536);    // 25,165,824 B

  prep_whh<<<dim3((128 * NG + 255) / 256), dim3(256), 0, stream>>>(whh, w16);

  for (int c = 0; c < NCHUNK; ++c) {
    gi_kernel<<<dim3(TCH, 4), dim3(256), 0, stream>>>(seq, emb, wih, bih, gi, c * TCH);
    rec_kernel<<<dim3(NB), dim3(512), 0, stream>>>(
        w16, gi, bhh, h_state, (c == NCHUNK - 1) ? out : nullptr, c);
  }
}

// Round 2
// 2401.099 us; speedup vs baseline: 1.3784x; 1.3784x over previous
//
#include <hip/hip_runtime.h>
#include <hip/hip_fp16.h>

#define TSEQ   2048
#define NB     64
#define NE     256
#define NH     256
#define NG     768
#define TCH    64
#define NCHUNK (TSEQ / TCH)

using half2_t = __attribute__((ext_vector_type(2))) _Float16;
union U4 { uint4 q; half2_t h[4]; };

__device__ __forceinline__ float dot2f(half2_t a, half2_t b, float c) {
#if __has_builtin(__builtin_amdgcn_fdot2)
  return __builtin_amdgcn_fdot2(a, b, c, false);
#else
  return c + (float)a[0] * (float)b[0] + (float)a[1] * (float)b[1];
#endif
}

__device__ __forceinline__ float fast_exp2(float x) {
#if __has_builtin(__builtin_amdgcn_exp2f)
  return __builtin_amdgcn_exp2f(x);
#else
  return exp2f(x);
#endif
}
__device__ __forceinline__ float fast_rcp(float x) {
#if __has_builtin(__builtin_amdgcn_rcpf)
  return __builtin_amdgcn_rcpf(x);
#else
  return 1.f / x;
#endif
}
__device__ __forceinline__ float sigm(float x) {
  // 1/(1+e^-x); x very negative -> exp2(+big)=inf -> rcp(inf)=0  (correct limit)
  return fast_rcp(1.f + fast_exp2(x * -1.44269504f));
}
__device__ __forceinline__ float tanh_fast(float x) {
  x = fminf(x, 15.f);                       // avoid inf/inf -> NaN
  float e = fast_exp2(x * 2.88539008f);     // e^(2x)
  return (e - 1.f) * fast_rcp(e + 1.f);
}

// ---------------------------------------------------------------------------
// Pack w_hh (fp32 [768][256]) into fp16 pairs: w16[((k2b*NG + row)<<2) | q]
// where k2 = 4*k2b + q indexes element pair (2*k2, 2*k2+1).
// ---------------------------------------------------------------------------
__global__ void prep_whh(const float* __restrict__ whh, unsigned int* __restrict__ w16) {
  int idx = blockIdx.x * 256 + threadIdx.x;
  if (idx >= 128 * NG) return;
  int row = idx % NG;
  int k2  = idx / NG;
  half2_t p;
  p[0] = (_Float16)whh[row * NH + 2 * k2];
  p[1] = (_Float16)whh[row * NH + 2 * k2 + 1];
  union { half2_t h; unsigned int u; } cvt;
  cvt.h = p;
  w16[(((k2 >> 2) * NG + row) << 2) | (k2 & 3)] = cvt.u;
}

// ---------------------------------------------------------------------------
// Fused per-chunk kernel.
//   blocks [0, rec_count)            : recurrence for `chunk` (1 block = 1 batch)
//   blocks [rec_count, rec_count+256): gi GEMM for the NEXT chunk into gi_dst
// rec blocks use 256 VGPR/wave -> exactly 1 WG/CU -> gi blocks land on other CUs.
// ---------------------------------------------------------------------------
__global__ __launch_bounds__(512) __attribute__((amdgpu_waves_per_eu(2, 2)))
void fused_kernel(const int* __restrict__ seq, const float* __restrict__ emb,
                  const float* __restrict__ wih, const float* __restrict__ bih,
                  const float* __restrict__ bhh, const unsigned int* __restrict__ w16,
                  const float* __restrict__ rec_gi, float* __restrict__ gi_dst,
                  int gi_t0, float* __restrict__ h_state, float* __restrict__ out,
                  int rec_count, int chunk)
{
  __shared__ __align__(16) _Float16 h16[2][NH];
  __shared__ __align__(16) float    xs[64][68];
  __shared__ __align__(16) float    wsh[192][68];
  __shared__ int tok[64];

  const int tid = threadIdx.x;

  if ((int)blockIdx.x < rec_count) {
    // ======================= recurrence =======================
    const int b    = blockIdx.x;
    const int lane = tid & 63;
    const int wv   = tid >> 6;
    const int jj   = lane & 31;
    const int s    = lane >> 5;          // k-half, partner lane is lane^32
    const int j    = wv * 32 + jj;       // hidden index 0..255

    // weights in registers: 3 gate rows x 64 half2 = 48 uint4 = 192 VGPRs
    uint4 wr[16], wz[16], wn[16];
#pragma unroll
    for (int i = 0; i < 16; ++i) {
      const int k2b = s * 16 + i;
      const unsigned int* base = w16 + (((size_t)k2b * NG) << 2);
      wr[i] = *(const uint4*)(base + ((size_t)j << 2));
      wz[i] = *(const uint4*)(base + ((size_t)(NH + j) << 2));
      wn[i] = *(const uint4*)(base + ((size_t)(2 * NH + j) << 2));
    }
    const float bn = bhh[2 * NH + j];    // only n-gate bias stays separate
    float hreg = 0.f;
    if (chunk != 0) hreg = h_state[b * NH + j];
    if (s == 0) h16[0][j] = (_Float16)hreg;
    __syncthreads();

    const float* gbase = rec_gi + (size_t)b * NG;
    float gr = gbase[j], gz = gbase[NH + j], gn = gbase[2 * NH + j];

#pragma unroll 1
    for (int t = 0; t < TCH; ++t) {
      // prefetch next step's input gates (hides under the dot loop)
      const int tn = (t + 1) & (TCH - 1);
      const float* gt = gbase + (size_t)tn * NB * NG;
      float grn = gt[j], gzn = gt[NH + j], gnn = gt[2 * NH + j];

      float ar = 0.f, az = 0.f, an = 0.f;
      const char* hb = (const char*)h16 + ((t & 1) << 9) + (s << 8);
#pragma unroll
      for (int i = 0; i < 16; ++i) {
        U4 hu; hu.q = *(const uint4*)(hb + (i << 4));   // wave-uniform per half -> broadcast
        U4 ru; ru.q = wr[i];
        U4 zu; zu.q = wz[i];
        U4 nu; nu.q = wn[i];
#pragma unroll
        for (int q = 0; q < 4; ++q) {
          ar = dot2f(hu.h[q], ru.h[q], ar);
          az = dot2f(hu.h[q], zu.h[q], az);
          an = dot2f(hu.h[q], nu.h[q], an);
        }
      }
      // combine the two k-halves inside the wave
      ar += __shfl_xor(ar, 32, 64);
      az += __shfl_xor(az, 32, 64);
      an += __shfl_xor(an, 32, 64);

      const float r = sigm(gr + ar);          // b_ih_r + b_hh_r folded into gi
      const float z = sigm(gz + az);          // b_ih_z + b_hh_z folded into gi
      const float n = tanh_fast(gn + r * (an + bn));
      hreg = n + z * (hreg - n);              // (1-z)*n + z*h

      if (s == 0) h16[(t + 1) & 1][j] = (_Float16)hreg;
      gr = grn; gz = gzn; gn = gnn;
      __syncthreads();
    }
    if (s == 0) {
      h_state[b * NH + j] = hreg;
      if (out) out[b * NH + j] = hreg;
    }
  } else {
    // ======================= gi GEMM ==========================
    const int gb = blockIdx.x - rec_count;
    const int tl = gb >> 2;                  // local timestep 0..63
    const int g0 = (gb & 3) * 192;
    const int t  = gi_t0 + tl;
    if (tid < 64) tok[tid] = seq[tid * TSEQ + t];
    const int tx = tid & 31;                 // 32 gate columns
    const int ty = tid >> 5;                 // 16 groups of 4 batch rows
    float acc[4][6];
#pragma unroll
    for (int i = 0; i < 4; ++i)
#pragma unroll
      for (int jj2 = 0; jj2 < 6; ++jj2) acc[i][jj2] = 0.f;

    for (int kb = 0; kb < 4; ++kb) {
      __syncthreads();                       // covers tok on first iter
#pragma unroll
      for (int it = 0; it < 2; ++it) {
        int i = it * 512 + tid;
        int r = i >> 4, c = i & 15;
        *(float4*)(&xs[r][c * 4]) =
            *(const float4*)(emb + (size_t)tok[r] * NE + kb * 64 + c * 4);
      }
#pragma unroll
      for (int it = 0; it < 6; ++it) {
        int i = it * 512 + tid;
        int r = i >> 4, c = i & 15;
        *(float4*)(&wsh[r][c * 4]) =
            *(const float4*)(wih + (size_t)(g0 + r) * NE + kb * 64 + c * 4);
      }
      __syncthreads();
#pragma unroll 4
      for (int k4 = 0; k4 < 16; ++k4) {
        float4 xf[4], wf[6];
#pragma unroll
        for (int i = 0; i < 4; ++i) xf[i] = *(const float4*)(&xs[ty * 4 + i][k4 * 4]);
#pragma unroll
        for (int jj2 = 0; jj2 < 6; ++jj2) wf[jj2] = *(const float4*)(&wsh[tx + 32 * jj2][k4 * 4]);
#pragma unroll
        for (int i = 0; i < 4; ++i)
#pragma unroll
          for (int jj2 = 0; jj2 < 6; ++jj2)
            acc[i][jj2] += xf[i].x * wf[jj2].x + xf[i].y * wf[jj2].y +
                           xf[i].z * wf[jj2].z + xf[i].w * wf[jj2].w;
      }
    }
    // epilogue: fold b_ih everywhere, b_hh for r/z gates only
#pragma unroll
    for (int i = 0; i < 4; ++i) {
      const int brow = ty * 4 + i;
      float* dst = gi_dst + ((size_t)(tl * NB + brow)) * NG + g0;
#pragma unroll
      for (int jj2 = 0; jj2 < 6; ++jj2) {
        const int col = tx + 32 * jj2;
        const int g = g0 + col;
        float bias = bih[g] + (g < 2 * NH ? bhh[g] : 0.f);
        dst[col] = acc[i][jj2] + bias;
      }
    }
  }
}

extern "C" void kernel_launch(void* const* d_in, const int* in_sizes, int n_in,
                              void* d_out, int out_size, void* d_ws, size_t ws_size,
                              hipStream_t stream) {
  (void)in_sizes; (void)n_in; (void)out_size; (void)ws_size;
  const int*   seq = (const int*)d_in[0];
  const float* emb = (const float*)d_in[1];
  const float* wih = (const float*)d_in[2];
  const float* whh = (const float*)d_in[3];
  const float* bih = (const float*)d_in[4];
  const float* bhh = (const float*)d_in[5];
  float* out = (float*)d_out;
  char*  ws  = (char*)d_ws;

  unsigned int* w16     = (unsigned int*)(ws);            // 393,216 B
  float*        h_state = (float*)(ws + 393216);          //  65,536 B
  float*        gi0     = (float*)(ws + 458752);          // 12,582,912 B
  float*        gi1     = (float*)(ws + 458752 + 12582912);

  prep_whh<<<dim3(384), dim3(256), 0, stream>>>(whh, w16);

  // prologue: gi for chunk 0 only
  fused_kernel<<<dim3(256), dim3(512), 0, stream>>>(
      seq, emb, wih, bih, bhh, w16,
      nullptr, gi0, 0, h_state, nullptr, 0, 0);

  for (int c = 0; c < NCHUNK; ++c) {
    float* rd   = (c & 1) ? gi1 : gi0;
    float* wr_  = (c & 1) ? gi0 : gi1;
    const bool last = (c == NCHUNK - 1);
    const int grid  = last ? NB : NB + 256;
    fused_kernel<<<dim3(grid), dim3(512), 0, stream>>>(
        seq, emb, wih, bih, bhh, w16,
        rd, last ? nullptr : wr_, (c + 1) * TCH, h_state,
        last ? out : nullptr, NB, c);
  }
}